// Round 10
// baseline (4663.530 us; speedup 1.0000x reference)
//
#include <hip/hip_runtime.h>
#include <stdint.h>

// Persistent-kernel LSTM, MI355X — R15: cohort software-pipelining on the
// proven R13 base (no new coherence assumptions; XCD-local line abandoned
// after two hangs — no HW scope exists between workgroup and agent).
//   R13 decomposition (7160cy/step): ~1600 byte-term + ~1800 compute +
//   ~3700 sync (poll races producers' stores -> retries).
//   R15: split each group's 16 samples into independent cohorts A(0-7)/B(8-15)
//   and interleave phases: pollA, computeA+storeA, pollB, computeB+storeB.
//   The h a WG polls was stored ONE FULL PHASE earlier (~2000cy slack) ->
//   attempt 1 lands fresh -> poll = single clean blocking load.
//   - Protocol per cohort = R13 exactly: bf16-pair h, tag bit = u32 LSB,
//     slot t&1, tag (t>>1)&1; load IS the barrier; per-lane masked retry;
//     loads double as MFMA A-fragments; drain-free LDS barriers.
//   - Only lanes lr<8 poll (8 samples, 16KB/WG/phase, zero redundancy);
//     4 shfls broadcast fragments to dup rows 8-15; C rows 8-15 are dups ->
//     LDS partial writes skipped for lq>=2 (half write traffic).
//   - part[8][4][2][8][17] = 34.8KB. Geometry = R13: 128 WGs x 512 thr,
//     4 groups x 32 WGs (32 hidden), 8-wave K-split, bfrag = 128 VGPRs.
// ws layout: [0, 256KB) h dbuf (bf16-pair, tagged) | [0x80000, +4MB) embW fp32

#define T_STEPS 1024
#define BATCH   64
#define EDIM    256
#define HDIM    1024

typedef float    f32x4  __attribute__((ext_vector_type(4)));
typedef short    bf16x8 __attribute__((ext_vector_type(8)));
typedef uint32_t u32x4  __attribute__((ext_vector_type(4)));

__device__ __forceinline__ unsigned short f2bf(float f) {
  union { float f; uint32_t u; } v; v.f = f;
  uint32_t r = (v.u + 0x7FFFu + ((v.u >> 16) & 1u)) >> 16;  // RNE
  return (unsigned short)r;
}
__device__ __forceinline__ float sigf(float x) { return 1.f / (1.f + __expf(-x)); }
__device__ __forceinline__ float tanh_fast(float x) {
  float ax = fabsf(x);
  float e  = __expf(-2.f * ax);
  float t  = (1.f - e) / (1.f + e);
  return copysignf(t, x);
}

__global__ void __launch_bounds__(256)
embw_kernel(const float* __restrict__ emb, const float* __restrict__ W_ih,
            const float* __restrict__ b_ih, const float* __restrict__ b_hh,
            float* __restrict__ embW)
{
  __shared__ float ev[EDIM];
  const int v   = blockIdx.y;
  const int col = blockIdx.x * 256 + threadIdx.x;
  ev[threadIdx.x] = emb[v * EDIM + threadIdx.x];
  __syncthreads();
  const float4* wr = (const float4*)(W_ih + (size_t)col * EDIM);
  float acc = b_ih[col] + b_hh[col];
#pragma unroll 4
  for (int e4 = 0; e4 < EDIM / 4; ++e4) {
    const float4 q = wr[e4];
    acc += ev[4*e4+0] * q.x + ev[4*e4+1] * q.y + ev[4*e4+2] * q.z + ev[4*e4+3] * q.w;
  }
  embW[(size_t)v * (4 * HDIM) + col] = acc;
}

// 4 coherent 16B loads + in-asm drain (R13-proven). "+v" keeps exec-masked
// lanes' previous values. Load AND wait in ONE asm region (R10 lesson).
#define ISSUE4_WAIT(VOFF)                                                   \
  asm volatile(                                                             \
    "global_load_dwordx4 %0, %4, %5 sc0 sc1\n\t"                            \
    "global_load_dwordx4 %1, %4, %5 offset:64 sc0 sc1\n\t"                  \
    "global_load_dwordx4 %2, %4, %5 offset:128 sc0 sc1\n\t"                 \
    "global_load_dwordx4 %3, %4, %5 offset:192 sc0 sc1\n\t"                 \
    "s_waitcnt vmcnt(0)"                                                    \
    : "+v"(r0), "+v"(r1), "+v"(r2), "+v"(r3)                                \
    : "v"(VOFF), "s"(hbuf)                                                  \
    : "memory")

#define TCHK(R) do { o |= (R.x ^ tagw); o |= (R.y ^ tagw);                  \
                     o |= (R.z ^ tagw); o |= (R.w ^ tagw); } while (0)

// freshness sweep -> bad (LSB, masked to polling lanes lr<8)
#define TAGCHK4() do { o = 0;                                               \
    TCHK(r0); TCHK(r1); TCHK(r2); TCHK(r3);                                 \
    bad = (o & 1u) & lrmask; } while (0)

#define BCAST(R) do {                                                       \
    R.x = (uint32_t)__shfl((int)R.x, src); R.y = (uint32_t)__shfl((int)R.y, src); \
    R.z = (uint32_t)__shfl((int)R.z, src); R.w = (uint32_t)__shfl((int)R.w, src); \
  } while (0)

// LDS-only barrier: order ds ops, leave VMEM (the h store) in flight.
#define LDS_BARRIER() do {                                                  \
    asm volatile("s_waitcnt lgkmcnt(0)" ::: "memory");                      \
    __builtin_amdgcn_s_barrier();                                           \
    __builtin_amdgcn_sched_barrier(0);                                      \
  } while (0)

// One cohort phase: gather, poll(prev h), MFMA, reduce, pointwise, store h.
#define DO_PHASE(cS, lastcS, tokS, slS, bS, VBASE)                          \
  {                                                                         \
    float gi = 0.f, gf = 0.f, gg = 0.f, go = 0.f;                           \
    if (act) {                                                              \
      const float* er = embW + (size_t)tokS * (4 * HDIM) + hb + j;          \
      gi = er[0]; gf = er[HDIM]; gg = er[2 * HDIM]; go = er[3 * HDIM];      \
    }                                                                       \
    const int tnext = (t + 1 < T_STEPS) ? (t + 1) : t;                      \
    const int tok_n = act ? tokens[tnext * BATCH + (bS)] : 0;               \
    if (t > 0) {                                                            \
      const uint32_t tagw = (uint32_t)(((t - 1) >> 1) & 1);                 \
      const uint32_t voff =                                                 \
          ((uint32_t)((t - 1) & 1)) * (BATCH * (HDIM / 2) * 4u) + (VBASE);  \
      u32x4 r0 = {0,0,0,0}, r1 = r0, r2 = r0, r3 = r0;                      \
      uint32_t o, bad;                                                      \
      if (lr < 8) { ISSUE4_WAIT(voff); }                                    \
      TAGCHK4();                                                            \
      while (__any(bad != 0)) {                                             \
        if (bad != 0) { ISSUE4_WAIT(voff); TAGCHK4(); }                     \
      }                                                                     \
      BCAST(r0); BCAST(r1); BCAST(r2); BCAST(r3);                           \
      f32x4 acc[4][2];                                                      \
      _Pragma("unroll")                                                     \
      for (int n = 0; n < 4; ++n)                                           \
        _Pragma("unroll")                                                   \
        for (int nt = 0; nt < 2; ++nt)                                      \
          acc[n][nt] = (f32x4){0.f, 0.f, 0.f, 0.f};                         \
      const u32x4 rr[4] = {r0, r1, r2, r3};                                 \
      _Pragma("unroll")                                                     \
      for (int ks = 0; ks < 4; ++ks) {                                      \
        union { u32x4 u; bf16x8 v; } au;                                    \
        au.u = rr[ks];                                                      \
        _Pragma("unroll")                                                   \
        for (int n = 0; n < 4; ++n)                                         \
          _Pragma("unroll")                                                 \
          for (int nt = 0; nt < 2; ++nt)                                    \
            acc[n][nt] = __builtin_amdgcn_mfma_f32_16x16x32_bf16(           \
                au.v, bfrag[n][nt][ks], acc[n][nt], 0, 0, 0);               \
      }                                                                     \
      if (lq < 2) {             /* rows 8-15 are dups: skip */              \
        _Pragma("unroll")                                                   \
        for (int n = 0; n < 4; ++n)                                         \
          _Pragma("unroll")                                                 \
          for (int nt = 0; nt < 2; ++nt)                                    \
            _Pragma("unroll")                                               \
            for (int r = 0; r < 4; ++r)                                     \
              part[w][n][nt][lq * 4 + r][lr] = acc[n][nt][r];               \
      }                                                                     \
    }                                                                       \
    LDS_BARRIER();                                                          \
    if (t > 0 && act) {                                                     \
      const int ntj = j >> 4, nj = j & 15;                                  \
      _Pragma("unroll")                                                     \
      for (int ww = 0; ww < 8; ++ww) {                                      \
        gi += part[ww][0][ntj][s][nj];                                      \
        gf += part[ww][1][ntj][s][nj];                                      \
        gg += part[ww][2][ntj][s][nj];                                      \
        go += part[ww][3][ntj][s][nj];                                      \
      }                                                                     \
    }                                                                       \
    const float cn = sigf(gf) * (cS) + sigf(gi) * tanh_fast(gg);            \
    const float hn = sigf(go) * tanh_fast(cn);                              \
    cS = cn;                                                                \
    if ((t == 0) || (t < (slS))) lastcS = cn;                               \
    const unsigned short hu = f2bf(hn);                                     \
    const int other = __shfl_xor((int)hu, 1);                               \
    if (act && (j & 1) == 0) {                                              \
      const uint32_t pk = (uint32_t)hu | ((uint32_t)(unsigned short)other << 16); \
      const uint32_t tu = (pk & ~1u) | (uint32_t)((t >> 1) & 1);            \
      __hip_atomic_store(hbuf + (t & 1) * (BATCH * (HDIM / 2))              \
                              + (bS) * (HDIM / 2) + ((hb + j) >> 1),        \
                         tu, __ATOMIC_RELAXED, __HIP_MEMORY_SCOPE_AGENT);   \
    }                                                                       \
    LDS_BARRIER();                                                          \
    tokS = tok_n;                                                           \
  }

__global__ void __launch_bounds__(512, 1)
lstm_kernel(const int* __restrict__ tokens, const int* __restrict__ seq_len,
            const float* __restrict__ W_hh, const float* __restrict__ embW,
            uint32_t* hbuf, float* __restrict__ out)
{
  const int tid = threadIdx.x;
  const int bid = blockIdx.x;     // 0..127
  const int g   = bid & 3;        // batch group (16 samples; cohorts 8+8)
  const int wig = bid >> 2;       // WG within group: 0..31
  const int hb  = wig << 5;       // hidden base (32 per WG)
  const int gs0 = g << 4;         // sample base (16 per group)
  const int w   = tid >> 6;       // wave 0..7 (K-split: 128 each)
  const int l   = tid & 63;
  const int lr  = l & 15;         // MFMA m / n index
  const int lq  = l >> 4;         // MFMA k-quad
  const uint32_t lrmask = (lr < 8) ? 1u : 0u;
  const int src = (lr < 8) ? l : (l - 8);  // shfl source for dup rows

  // ---- stage W_hh slice into registers as bf16 MFMA B-fragments ----
  bf16x8 bfrag[4][2][4];          // [gate][ntile][kstep] = 128 VGPRs
#pragma unroll
  for (int n = 0; n < 4; ++n)
#pragma unroll
    for (int nt = 0; nt < 2; ++nt) {
      const float* wrow = W_hh + (size_t)(n * HDIM + hb + nt * 16 + lr) * HDIM
                               + w * 128 + lq * 8;
#pragma unroll
      for (int ks = 0; ks < 4; ++ks) {
        union { bf16x8 v; unsigned short u[8]; } bu;
#pragma unroll
        for (int e = 0; e < 8; ++e) bu.u[e] = f2bf(wrow[ks * 32 + e]);
        bfrag[n][nt][ks] = bu.v;
      }
    }

  const int act = (tid < 256);    // pointwise: 8 samples x 32 hidden per phase
  const int s   = (tid >> 5) & 7; // sample-local 0..7
  const int j   = tid & 31;       // hidden-local 0..31
  const int bA  = gs0 + s;        // cohort A sample
  const int bB  = gs0 + 8 + s;    // cohort B sample
  const int slA = act ? seq_len[bA] : 0;
  const int slB = act ? seq_len[bB] : 0;
  float cA = 0.f, lastcA = 0.f, cB = 0.f, lastcB = 0.f;

  __shared__ float part[8][4][2][8][17];   // 34.8 KB (rows 0-7 only)

  // poll bases: lanes lr<8 read sample row gs0+lr (A) / gs0+8+lr (B)
  const uint32_t voffA =
      (uint32_t)(((gs0 + (lr & 7)) * (HDIM / 2) + w * 64 + lq * 4) * 4);
  const uint32_t voffB = voffA + (uint32_t)(8 * (HDIM / 2) * 4);

  int tokA = act ? tokens[bA] : 0;
  int tokB = act ? tokens[bB] : 0;

  for (int t = 0; t < T_STEPS; ++t) {
    DO_PHASE(cA, lastcA, tokA, slA, bA, voffA);   // phase A
    DO_PHASE(cB, lastcB, tokB, slB, bB, voffB);   // phase B
  }

  if (act) {
    out[(size_t)bA * HDIM + hb + j] = lastcA;
    out[(size_t)bB * HDIM + hb + j] = lastcB;
  }
}

extern "C" void kernel_launch(void* const* d_in, const int* in_sizes, int n_in,
                              void* d_out, int out_size, void* d_ws, size_t ws_size,
                              hipStream_t stream) {
  const int*   tokens = (const int*)d_in[0];
  const int*   seqlen = (const int*)d_in[1];
  const float* emb    = (const float*)d_in[2];
  const float* W_ih   = (const float*)d_in[3];
  const float* W_hh   = (const float*)d_in[4];
  const float* b_ih   = (const float*)d_in[5];
  const float* b_hh   = (const float*)d_in[6];
  float* out = (float*)d_out;

  uint8_t*  ws   = (uint8_t*)d_ws;
  uint32_t* hbuf = (uint32_t*)ws;               // 2 * 64*512 u32 = 256 KB
  float*    embW = (float*)(ws + 0x80000);      // 256 * 4096 fp32 = 4 MB

  // init h dbuf to 0xFF: u32 LSB=1 != first expected tag (0) for both slots
  hipMemsetAsync(ws, 0xFF, 2 * BATCH * (HDIM / 2) * 4, stream);
  embw_kernel<<<dim3(16, 256), 256, 0, stream>>>(emb, W_ih, b_ih, b_hh, embW);
  lstm_kernel<<<dim3(128), 512, 0, stream>>>(tokens, seqlen, W_hh, embW, hbuf, out);
}